// Round 1
// baseline (1068.822 us; speedup 1.0000x reference)
//
#include <hip/hip_runtime.h>
#include <stdint.h>

typedef __attribute__((ext_vector_type(8))) short short8;
typedef __attribute__((ext_vector_type(4))) float f32x4;
typedef __attribute__((ext_vector_type(4))) unsigned short u16x4;

__device__ __forceinline__ unsigned short f2bf(float x){
  union { float f; unsigned int u; } v; v.f = x;
  unsigned int r = v.u + 0x7fffu + ((v.u >> 16) & 1u);
  return (unsigned short)(r >> 16);
}

__device__ __forceinline__ f32x4 mfma16(short8 a, short8 b, f32x4 c){
  return __builtin_amdgcn_mfma_f32_16x16x32_bf16(a, b, c, 0, 0, 0);
}

__device__ __forceinline__ void async16(const void* g, void* l){
  __builtin_amdgcn_global_load_lds(
      (__attribute__((address_space(1))) void*)g,
      (__attribute__((address_space(3))) void*)l, 16, 0, 0);
}

// ---------- elementwise: out_bf16 = a (+ b) ----------
__global__ __launch_bounds__(256) void k_prep(const float4* __restrict__ a,
                                              const float4* __restrict__ b,
                                              u16x4* __restrict__ o, int n4){
  int i = blockIdx.x * 256 + threadIdx.x;
  if (i >= n4) return;
  float4 x = a[i];
  if (b){ float4 y = b[i]; x.x += y.x; x.y += y.y; x.z += y.z; x.w += y.w; }
  u16x4 r; r.x = f2bf(x.x); r.y = f2bf(x.y); r.z = f2bf(x.z); r.w = f2bf(x.w);
  o[i] = r;
}

// ---------- GEMM: C[m][n] = sum_k A[m][k]*W[n][k] (+bias)*scale ----------
// K = 1024 fixed. 128x128 tile, BK=32, 256 threads (2x2 waves of 64x64).
// LDS granule layout: granule g = qq*128 + row (qq = k-chunk of 8), 16B each.
// MODE 0: bf16 out at [B,H,seq,64], rows r = seq*2+b.  MODE 1: fp32 out at
// [T,B,D], rows r = b*1024+t.
template<int MODE>
__global__ __launch_bounds__(256,2) void k_gemm(const unsigned short* __restrict__ A,
    const unsigned short* __restrict__ W, const float* __restrict__ bias,
    void* __restrict__ outp, int M, float scale)
{
  __shared__ unsigned short lA[128*32];
  __shared__ unsigned short lB[128*32];
  const int tid = threadIdx.x, lane = tid & 63, w = tid >> 6;
  const int quad = lane >> 4, m16 = lane & 15;
  const int wm = w & 1, wn = w >> 1;
  const int row0 = blockIdx.x * 128, col0 = blockIdx.y * 128;
  const int g0 = w*64 + lane, g1 = (w+4)*64 + lane;
  const int r0g = g0 & 127, q0g = g0 >> 7;
  const int r1g = g1 & 127, q1g = g1 >> 7;
  const unsigned short* Ab = A + (size_t)row0 * 1024;
  const unsigned short* Bb = W + (size_t)col0 * 1024;
  f32x4 acc[4][4] = {};
  for (int k0 = 0; k0 < 1024; k0 += 32){
    async16(Ab + (size_t)r0g*1024 + k0 + q0g*8, &lA[w*512]);
    async16(Ab + (size_t)r1g*1024 + k0 + q1g*8, &lA[(w+4)*512]);
    async16(Bb + (size_t)r0g*1024 + k0 + q0g*8, &lB[w*512]);
    async16(Bb + (size_t)r1g*1024 + k0 + q1g*8, &lB[(w+4)*512]);
    __syncthreads();
    short8 af[4], bfr[4];
    #pragma unroll
    for (int mt = 0; mt < 4; ++mt)
      af[mt] = *(const short8*)&lA[(quad*128 + wm*64 + mt*16 + m16)*8];
    #pragma unroll
    for (int nt = 0; nt < 4; ++nt)
      bfr[nt] = *(const short8*)&lB[(quad*128 + wn*64 + nt*16 + m16)*8];
    #pragma unroll
    for (int mt = 0; mt < 4; ++mt)
      #pragma unroll
      for (int nt = 0; nt < 4; ++nt)
        acc[mt][nt] = mfma16(af[mt], bfr[nt], acc[mt][nt]);
    __syncthreads();
  }
  if (MODE == 0){
    unsigned short* out16 = (unsigned short*)outp;
    const int SEQ = M >> 1;
    #pragma unroll
    for (int nt = 0; nt < 4; ++nt){
      const int n = col0 + wn*64 + nt*16 + m16;
      const float bvv = bias[n];
      const int h = n >> 6, d = n & 63;
      #pragma unroll
      for (int mt = 0; mt < 4; ++mt){
        const int rbase = row0 + wm*64 + mt*16 + quad*4;
        #pragma unroll
        for (int r = 0; r < 4; ++r){
          const int rr = rbase + r;
          const int seq = rr >> 1, bb = rr & 1;
          const float vv = (acc[mt][nt][r] + bvv) * scale;
          out16[(((size_t)(bb*16 + h) * SEQ + seq) << 6) + d] = f2bf(vv);
        }
      }
    }
  } else {
    float* outf = (float*)outp;
    #pragma unroll
    for (int nt = 0; nt < 4; ++nt){
      const int n = col0 + wn*64 + nt*16 + m16;
      const float bvv = bias[n];
      #pragma unroll
      for (int mt = 0; mt < 4; ++mt){
        const int rbase = row0 + wm*64 + mt*16 + quad*4;
        #pragma unroll
        for (int r = 0; r < 4; ++r){
          const int rr = rbase + r;
          const int tt = rr & 1023, bb = rr >> 10;
          outf[(((size_t)tt*2 + bb) << 10) + n] = acc[mt][nt][r] + bvv;
        }
      }
    }
  }
}

// ---------- V [BH,4096,64] -> VT [BH,64,4096] (bf16) ----------
__global__ __launch_bounds__(256) void k_tr(const unsigned short* __restrict__ V,
                                            unsigned short* __restrict__ VT){
  __shared__ unsigned short t[64*73];   // [d][s], stride 73 breaks conflicts
  const int tid = threadIdx.x;
  const int bh = blockIdx.x >> 6;
  const int s0 = (blockIdx.x & 63) << 6;
  #pragma unroll
  for (int j = 0; j < 2; ++j){
    int g = j*256 + tid;
    int s = g >> 3, d0 = (g & 7)*8;
    short8 x = *(const short8*)&V[(((size_t)bh*4096 + s0 + s) << 6) + d0];
    #pragma unroll
    for (int k = 0; k < 8; ++k)
      t[(d0 + k)*73 + s] = (unsigned short)x[k];
  }
  __syncthreads();
  #pragma unroll
  for (int j = 0; j < 2; ++j){
    int g = j*256 + tid;
    int d = g >> 3, sc = (g & 7)*8;
    short8 r;
    #pragma unroll
    for (int k = 0; k < 8; ++k)
      r[k] = (short)t[d*73 + sc + k];
    *(short8*)&VT[(((size_t)bh*64 + d) << 12) + s0 + sc] = r;
  }
}

// ---------- flash attention ----------
// grid 512 = BH(32) x Ttiles(16); 4 waves x 16 Q-rows; S tiles of 64.
__global__ __launch_bounds__(256,2) void k_flash(const unsigned short* __restrict__ Qp,
    const unsigned short* __restrict__ Kp, const unsigned short* __restrict__ VTp,
    const float* __restrict__ mask, unsigned short* __restrict__ ctx)
{
  __shared__ unsigned short pl[4096];   // per-wave 1 KB P staging (granule layout)
  const int tid = threadIdx.x, lane = tid & 63, w = tid >> 6;
  const int quad = lane >> 4, m16 = lane & 15;
  const int bh = blockIdx.x >> 4;
  const int t0 = ((blockIdx.x & 15) << 6) + w*16;
  short8 qa0, qa1;
  {
    const unsigned short* qp = Qp + (((size_t)bh*1024 + t0 + m16) << 6) + quad*8;
    qa0 = *(const short8*)qp;
    qa1 = *(const short8*)(qp + 32);
  }
  const unsigned short* kb = Kp + (((size_t)bh*4096 + m16) << 6) + quad*8;
  const unsigned short* vb = VTp + (((size_t)(bh*64 + m16)) << 12) + quad*8;
  const float* mb = mask + ((size_t)bh*1024 + t0 + quad*4) * 4096 + m16;
  unsigned short* pw = &pl[w*1024];
  const unsigned short* prd0 = &pl[w*1024 + (quad*16 + m16)*8];
  const unsigned short* prd1 = &pl[w*1024 + ((quad+4)*16 + m16)*8];
  const int pwbase = (m16 >> 3)*128 + quad*32 + (m16 & 7);
  f32x4 Oa[4] = {};
  float mrow[4], lrow[4];
  #pragma unroll
  for (int r = 0; r < 4; ++r){ mrow[r] = -1e30f; lrow[r] = 0.f; }
  const f32x4 zero4 = {0.f, 0.f, 0.f, 0.f};
  for (int s0 = 0; s0 < 4096; s0 += 64){
    f32x4 sc[4];
    #pragma unroll
    for (int c = 0; c < 4; ++c){
      const unsigned short* kp = kb + ((size_t)(s0 + c*16) << 6);
      short8 kf0 = *(const short8*)kp;
      short8 kf1 = *(const short8*)(kp + 32);
      f32x4 z = mfma16(qa0, kf0, zero4);
      sc[c] = mfma16(qa1, kf1, z);
    }
    const float* mp = mb + s0;
    #pragma unroll
    for (int c = 0; c < 4; ++c)
      #pragma unroll
      for (int r = 0; r < 4; ++r)
        sc[c][r] += __builtin_nontemporal_load(mp + (size_t)r*4096 + c*16);
    float rmax[4];
    #pragma unroll
    for (int r = 0; r < 4; ++r)
      rmax[r] = fmaxf(fmaxf(sc[0][r], sc[1][r]), fmaxf(sc[2][r], sc[3][r]));
    #pragma unroll
    for (int off = 1; off <= 8; off <<= 1)
      #pragma unroll
      for (int r = 0; r < 4; ++r)
        rmax[r] = fmaxf(rmax[r], __shfl_xor(rmax[r], off, 64));
    float al[4], rsum[4];
    #pragma unroll
    for (int r = 0; r < 4; ++r){
      float mn = fmaxf(mrow[r], rmax[r]);
      al[r] = __expf(mrow[r] - mn);
      mrow[r] = mn;
      rsum[r] = 0.f;
    }
    #pragma unroll
    for (int c = 0; c < 4; ++c)
      #pragma unroll
      for (int r = 0; r < 4; ++r){
        float p = __expf(sc[c][r] - mrow[r]);
        sc[c][r] = p;
        rsum[r] += p;
      }
    #pragma unroll
    for (int off = 1; off <= 8; off <<= 1)
      #pragma unroll
      for (int r = 0; r < 4; ++r)
        rsum[r] += __shfl_xor(rsum[r], off, 64);
    #pragma unroll
    for (int r = 0; r < 4; ++r)
      lrow[r] = lrow[r]*al[r] + rsum[r];
    #pragma unroll
    for (int cn = 0; cn < 4; ++cn)
      #pragma unroll
      for (int r = 0; r < 4; ++r)
        Oa[cn][r] *= al[r];
    // P -> LDS (per-wave region; same-wave DS is in-order, wait then read)
    #pragma unroll
    for (int c = 0; c < 4; ++c)
      #pragma unroll
      for (int r = 0; r < 4; ++r)
        pw[pwbase + c*256 + r*8] = f2bf(sc[c][r]);
    asm volatile("s_waitcnt lgkmcnt(0)" ::: "memory");
    short8 pa0 = *(const short8*)prd0;
    short8 pa1 = *(const short8*)prd1;
    #pragma unroll
    for (int cn = 0; cn < 4; ++cn){
      const unsigned short* vp = vb + ((size_t)cn << 16) + s0;
      short8 v0 = *(const short8*)vp;
      short8 v1 = *(const short8*)(vp + 32);
      Oa[cn] = mfma16(pa0, v0, Oa[cn]);
      Oa[cn] = mfma16(pa1, v1, Oa[cn]);
    }
  }
  const int b = bh >> 4, h = bh & 15;
  unsigned short* op = ctx + (((size_t)b*1024 + t0 + quad*4) << 10) + h*64 + m16;
  #pragma unroll
  for (int r = 0; r < 4; ++r){
    float inv = 1.f / lrow[r];
    #pragma unroll
    for (int cn = 0; cn < 4; ++cn)
      op[((size_t)r << 10) + cn*16] = f2bf(Oa[cn][r]*inv);
  }
}

extern "C" void kernel_launch(void* const* d_in, const int* in_sizes, int n_in,
                              void* d_out, int out_size, void* d_ws, size_t ws_size,
                              hipStream_t stream)
{
  (void)in_sizes; (void)n_in; (void)out_size; (void)ws_size;
  const float* hs    = (const float*)d_in[0];
  const float* mask  = (const float*)d_in[1];
  const float* pos   = (const float*)d_in[2];
  const float* kv    = (const float*)d_in[3];
  const float* kvpos = (const float*)d_in[4];
  const float* Wq = (const float*)d_in[5];  const float* biq = (const float*)d_in[6];
  const float* Wk = (const float*)d_in[7];  const float* bik = (const float*)d_in[8];
  const float* Wv = (const float*)d_in[9];  const float* biv = (const float*)d_in[10];
  const float* Wo = (const float*)d_in[11]; const float* bio = (const float*)d_in[12];
  float* out = (float*)d_out;
  char* ws = (char*)d_ws;
  // byte offsets (MB); overlays are safe by stream ordering:
  //   Vb overlays Ak (Ak dead after K-GEMM), VTb overlays Av, ctx overlays Wqb/Wkb.
  unsigned short* Aq  = (unsigned short*)(ws + ( 0ull << 20));  // 4 MB
  unsigned short* Ak  = (unsigned short*)(ws + ( 4ull << 20));  // 16 MB
  unsigned short* Av  = (unsigned short*)(ws + (20ull << 20));  // 16 MB
  unsigned short* Wqb = (unsigned short*)(ws + (36ull << 20));  // 2 MB
  unsigned short* Wkb = (unsigned short*)(ws + (38ull << 20));  // 2 MB
  unsigned short* Wvb = (unsigned short*)(ws + (40ull << 20));  // 2 MB
  unsigned short* Wob = (unsigned short*)(ws + (42ull << 20));  // 2 MB
  unsigned short* Qb  = (unsigned short*)(ws + (44ull << 20));  // 4 MB
  unsigned short* Kb  = (unsigned short*)(ws + (48ull << 20));  // 16 MB (end 64 MB)
  unsigned short* Vb  = (unsigned short*)(ws + ( 4ull << 20));  // overlay Ak
  unsigned short* VTb = (unsigned short*)(ws + (20ull << 20));  // overlay Av
  unsigned short* ctx = (unsigned short*)(ws + (36ull << 20));  // overlay Wqb/Wkb

  k_prep<<<dim3(2048), dim3(256), 0, stream>>>((const float4*)hs, (const float4*)pos,
                                               (u16x4*)Aq, 524288);
  k_prep<<<dim3(8192), dim3(256), 0, stream>>>((const float4*)kv, (const float4*)kvpos,
                                               (u16x4*)Ak, 2097152);
  k_prep<<<dim3(8192), dim3(256), 0, stream>>>((const float4*)kv, nullptr,
                                               (u16x4*)Av, 2097152);
  k_prep<<<dim3(1024), dim3(256), 0, stream>>>((const float4*)Wq, nullptr,
                                               (u16x4*)Wqb, 262144);
  k_prep<<<dim3(1024), dim3(256), 0, stream>>>((const float4*)Wk, nullptr,
                                               (u16x4*)Wkb, 262144);
  k_prep<<<dim3(1024), dim3(256), 0, stream>>>((const float4*)Wv, nullptr,
                                               (u16x4*)Wvb, 262144);
  k_prep<<<dim3(1024), dim3(256), 0, stream>>>((const float4*)Wo, nullptr,
                                               (u16x4*)Wob, 262144);

  k_gemm<0><<<dim3(16, 8), dim3(256), 0, stream>>>(Aq, Wqb, biq, Qb, 2048, 0.125f);
  k_gemm<0><<<dim3(64, 8), dim3(256), 0, stream>>>(Ak, Wkb, bik, Kb, 8192, 1.0f);
  k_gemm<0><<<dim3(64, 8), dim3(256), 0, stream>>>(Av, Wvb, biv, Vb, 8192, 1.0f);
  k_tr<<<dim3(2048), dim3(256), 0, stream>>>(Vb, VTb);
  k_flash<<<dim3(512), dim3(256), 0, stream>>>(Qb, Kb, VTb, mask, ctx);
  k_gemm<1><<<dim3(16, 8), dim3(256), 0, stream>>>(ctx, Wob, bio, out, 2048, 1.0f);
}

// Round 2
// 1052.158 us; speedup vs baseline: 1.0158x; 1.0158x over previous
//
#include <hip/hip_runtime.h>
#include <stdint.h>

typedef __attribute__((ext_vector_type(8))) short short8;
typedef __attribute__((ext_vector_type(4))) float f32x4;
typedef __attribute__((ext_vector_type(4))) unsigned short u16x4;

__device__ __forceinline__ unsigned short f2bf(float x){
  union { float f; unsigned int u; } v; v.f = x;
  unsigned int r = v.u + 0x7fffu + ((v.u >> 16) & 1u);
  return (unsigned short)(r >> 16);
}

__device__ __forceinline__ f32x4 mfma16(short8 a, short8 b, f32x4 c){
  return __builtin_amdgcn_mfma_f32_16x16x32_bf16(a, b, c, 0, 0, 0);
}

__device__ __forceinline__ void async16(const void* g, void* l){
  __builtin_amdgcn_global_load_lds(
      (__attribute__((address_space(1))) void*)g,
      (__attribute__((address_space(3))) void*)l, 16, 0, 0);
}

__device__ __forceinline__ u16x4 cvt4(float4 x){
  u16x4 r; r.x = f2bf(x.x); r.y = f2bf(x.y); r.z = f2bf(x.z); r.w = f2bf(x.w);
  return r;
}

// ---------- fused elementwise prep: all bf16 conversions in one launch ----------
// regions (float4 units): [0,524288) hs+pos->Aq ; [524288,2621440) kv(,+kvpos)->Av,Ak ;
// then 4x 262144 for Wq,Wk,Wv,Wo.
__global__ __launch_bounds__(256) void k_prep_all(
    const float4* __restrict__ hs, const float4* __restrict__ pos,
    const float4* __restrict__ kv, const float4* __restrict__ kvpos,
    const float4* __restrict__ Wq, const float4* __restrict__ Wk,
    const float4* __restrict__ Wv, const float4* __restrict__ Wo,
    u16x4* __restrict__ Aq, u16x4* __restrict__ Ak, u16x4* __restrict__ Av,
    u16x4* __restrict__ Wqb, u16x4* __restrict__ Wkb,
    u16x4* __restrict__ Wvb, u16x4* __restrict__ Wob)
{
  int i = blockIdx.x * 256 + threadIdx.x;
  if (i < 524288){
    float4 a = hs[i], b = pos[i];
    a.x += b.x; a.y += b.y; a.z += b.z; a.w += b.w;
    Aq[i] = cvt4(a);
  } else if (i < 2621440){
    int j = i - 524288;
    float4 a = kv[j], b = kvpos[j];
    Av[j] = cvt4(a);
    a.x += b.x; a.y += b.y; a.z += b.z; a.w += b.w;
    Ak[j] = cvt4(a);
  } else if (i < 2883584){
    int j = i - 2621440; Wqb[j] = cvt4(Wq[j]);
  } else if (i < 3145728){
    int j = i - 2883584; Wkb[j] = cvt4(Wk[j]);
  } else if (i < 3407872){
    int j = i - 3145728; Wvb[j] = cvt4(Wv[j]);
  } else {
    int j = i - 3407872; Wob[j] = cvt4(Wo[j]);
  }
}

// ---------- GEMM: C[m][n] = sum_k A[m][k]*W[n][k] (+bias)*scale ----------
// K = 1024 fixed. 128x128 tile, BK=32, 256 threads (2x2 waves of 64x64).
// MODE 0: bf16 out [B*H, seq, 64], rows rr = seq*2+b (Q/K).
// MODE 1: fp32 out [T, B, D], rows rr = b*1024+t (final output).
// MODE 2: bf16 V^T out [B*H, 64, 4096], rows rr = seq*2+b (V, transposed store).
template<int MODE>
__global__ __launch_bounds__(256,2) void k_gemm(const unsigned short* __restrict__ A,
    const unsigned short* __restrict__ W, const float* __restrict__ bias,
    void* __restrict__ outp, int M, float scale)
{
  __shared__ unsigned short lA[128*32];
  __shared__ unsigned short lB[128*32];
  const int tid = threadIdx.x, lane = tid & 63, w = tid >> 6;
  const int quad = lane >> 4, m16 = lane & 15;
  const int wm = w & 1, wn = w >> 1;
  const int row0 = blockIdx.x * 128, col0 = blockIdx.y * 128;
  const int g0 = w*64 + lane, g1 = (w+4)*64 + lane;
  const int r0g = g0 & 127, q0g = g0 >> 7;
  const int r1g = g1 & 127, q1g = g1 >> 7;
  const unsigned short* Ab = A + (size_t)row0 * 1024;
  const unsigned short* Bb = W + (size_t)col0 * 1024;
  f32x4 acc[4][4] = {};
  for (int k0 = 0; k0 < 1024; k0 += 32){
    async16(Ab + (size_t)r0g*1024 + k0 + q0g*8, &lA[w*512]);
    async16(Ab + (size_t)r1g*1024 + k0 + q1g*8, &lA[(w+4)*512]);
    async16(Bb + (size_t)r0g*1024 + k0 + q0g*8, &lB[w*512]);
    async16(Bb + (size_t)r1g*1024 + k0 + q1g*8, &lB[(w+4)*512]);
    __syncthreads();
    short8 af[4], bfr[4];
    #pragma unroll
    for (int mt = 0; mt < 4; ++mt)
      af[mt] = *(const short8*)&lA[(quad*128 + wm*64 + mt*16 + m16)*8];
    #pragma unroll
    for (int nt = 0; nt < 4; ++nt)
      bfr[nt] = *(const short8*)&lB[(quad*128 + wn*64 + nt*16 + m16)*8];
    #pragma unroll
    for (int mt = 0; mt < 4; ++mt)
      #pragma unroll
      for (int nt = 0; nt < 4; ++nt)
        acc[mt][nt] = mfma16(af[mt], bfr[nt], acc[mt][nt]);
    __syncthreads();
  }
  if (MODE == 0){
    unsigned short* out16 = (unsigned short*)outp;
    const int SEQ = M >> 1;
    #pragma unroll
    for (int nt = 0; nt < 4; ++nt){
      const int n = col0 + wn*64 + nt*16 + m16;
      const float bvv = bias[n];
      const int h = n >> 6, d = n & 63;
      #pragma unroll
      for (int mt = 0; mt < 4; ++mt){
        const int rbase = row0 + wm*64 + mt*16 + quad*4;
        #pragma unroll
        for (int r = 0; r < 4; ++r){
          const int rr = rbase + r;
          const int seq = rr >> 1, bb = rr & 1;
          const float vv = (acc[mt][nt][r] + bvv) * scale;
          out16[(((size_t)(bb*16 + h) * SEQ + seq) << 6) + d] = f2bf(vv);
        }
      }
    }
  } else if (MODE == 1){
    float* outf = (float*)outp;
    #pragma unroll
    for (int nt = 0; nt < 4; ++nt){
      const int n = col0 + wn*64 + nt*16 + m16;
      const float bvv = bias[n];
      #pragma unroll
      for (int mt = 0; mt < 4; ++mt){
        const int rbase = row0 + wm*64 + mt*16 + quad*4;
        #pragma unroll
        for (int r = 0; r < 4; ++r){
          const int rr = rbase + r;
          const int tt = rr & 1023, bb = rr >> 10;
          outf[(((size_t)tt*2 + bb) << 10) + n] = acc[mt][nt][r] + bvv;
        }
      }
    }
  } else {
    // V^T: out[(bb*16+h)*64 + d][seq], dims [32][64][4096]
    unsigned short* out16 = (unsigned short*)outp;
    #pragma unroll
    for (int nt = 0; nt < 4; ++nt){
      const int n = col0 + wn*64 + nt*16 + m16;
      const float bvv = bias[n];
      const int h = n >> 6, d = n & 63;
      #pragma unroll
      for (int mt = 0; mt < 4; ++mt){
        const int rbase = row0 + wm*64 + mt*16 + quad*4;
        #pragma unroll
        for (int r = 0; r < 4; ++r){
          const int rr = rbase + r;
          const int seq = rr >> 1, bb = rr & 1;
          out16[(((size_t)((bb*16 + h)*64 + d)) << 12) + seq] = f2bf(acc[mt][nt][r] + bvv);
        }
      }
    }
  }
}

// ---------- flash attention, software-pipelined ----------
// grid 512 = BH(32) x Ttiles(16); 4 waves x 16 Q-rows; S tiles of 64.
// K+mask for tile i+1 prefetched before softmax of tile i; V issued pre-fence.
__global__ __launch_bounds__(256,2) void k_flash(const unsigned short* __restrict__ Qp,
    const unsigned short* __restrict__ Kp, const unsigned short* __restrict__ VTp,
    const float* __restrict__ mask, unsigned short* __restrict__ ctx)
{
  __shared__ unsigned short pl[4096];   // per-wave 2 KB P staging, XOR-swizzled granules
  const int tid = threadIdx.x, lane = tid & 63, w = tid >> 6;
  const int quad = lane >> 4, m16 = lane & 15;
  const int bh = blockIdx.x >> 4;
  const int t0 = ((blockIdx.x & 15) << 6) + w*16;
  short8 qa0, qa1;
  {
    const unsigned short* qp = Qp + (((size_t)bh*1024 + t0 + m16) << 6) + quad*8;
    qa0 = *(const short8*)qp;
    qa1 = *(const short8*)(qp + 32);
  }
  const unsigned short* kb = Kp + (((size_t)bh*4096 + m16) << 6) + quad*8;
  const unsigned short* vb = VTp + (((size_t)(bh*64 + m16)) << 12) + quad*8;
  const float* mb = mask + ((size_t)bh*1024 + t0 + quad*4) * 4096 + m16;
  unsigned short* pw = &pl[w*1024];
  const unsigned short* prd0 = &pl[w*1024 + (quad*16 + (m16 ^ quad))*8];
  const unsigned short* prd1 = &pl[w*1024 + ((quad+4)*16 + (m16 ^ (quad+4)))*8];
  f32x4 Oa[4] = {};
  float mrow[4], lrow[4];
  #pragma unroll
  for (int r = 0; r < 4; ++r){ mrow[r] = -1e30f; lrow[r] = 0.f; }
  const f32x4 zero4 = {0.f, 0.f, 0.f, 0.f};

  short8 kA[8], kB[8];
  float mA[16], mB[16];

  auto LK = [&](int s0, short8* kf){
    #pragma unroll
    for (int c = 0; c < 4; ++c){
      const unsigned short* kp = kb + ((size_t)(s0 + c*16) << 6);
      kf[2*c]   = *(const short8*)kp;
      kf[2*c+1] = *(const short8*)(kp + 32);
    }
  };
  auto LM = [&](int s0, float* mf){
    const float* mp = mb + s0;
    #pragma unroll
    for (int c = 0; c < 4; ++c)
      #pragma unroll
      for (int r = 0; r < 4; ++r)
        mf[c*4+r] = __builtin_nontemporal_load(mp + (size_t)r*4096 + c*16);
  };
  auto PROC = [&](int s0, const short8* kf, const float* mf){
    f32x4 sc[4];
    #pragma unroll
    for (int c = 0; c < 4; ++c){
      f32x4 z = mfma16(qa0, kf[2*c], zero4);
      sc[c] = mfma16(qa1, kf[2*c+1], z);
    }
    // V loads issued early: latency hides under softmax VALU work
    short8 vf[8];
    #pragma unroll
    for (int cn = 0; cn < 4; ++cn){
      const unsigned short* vp = vb + ((size_t)cn << 16) + s0;
      vf[2*cn]   = *(const short8*)vp;
      vf[2*cn+1] = *(const short8*)(vp + 32);
    }
    #pragma unroll
    for (int c = 0; c < 4; ++c)
      #pragma unroll
      for (int r = 0; r < 4; ++r)
        sc[c][r] += mf[c*4+r];
    float rmax[4];
    #pragma unroll
    for (int r = 0; r < 4; ++r)
      rmax[r] = fmaxf(fmaxf(sc[0][r], sc[1][r]), fmaxf(sc[2][r], sc[3][r]));
    #pragma unroll
    for (int off = 1; off <= 8; off <<= 1)
      #pragma unroll
      for (int r = 0; r < 4; ++r)
        rmax[r] = fmaxf(rmax[r], __shfl_xor(rmax[r], off, 64));
    float al[4], rsum[4];
    #pragma unroll
    for (int r = 0; r < 4; ++r){
      float mn = fmaxf(mrow[r], rmax[r]);
      al[r] = __expf(mrow[r] - mn);
      mrow[r] = mn;
      rsum[r] = 0.f;
    }
    #pragma unroll
    for (int c = 0; c < 4; ++c)
      #pragma unroll
      for (int r = 0; r < 4; ++r){
        float p = __expf(sc[c][r] - mrow[r]);
        sc[c][r] = p;
        rsum[r] += p;
      }
    #pragma unroll
    for (int off = 1; off <= 8; off <<= 1)
      #pragma unroll
      for (int r = 0; r < 4; ++r)
        rsum[r] += __shfl_xor(rsum[r], off, 64);
    #pragma unroll
    for (int r = 0; r < 4; ++r)
      lrow[r] = lrow[r]*al[r] + rsum[r];
    #pragma unroll
    for (int cn = 0; cn < 4; ++cn)
      #pragma unroll
      for (int r = 0; r < 4; ++r)
        Oa[cn][r] *= al[r];
    // P -> LDS (XOR-swizzled: 16 banks instead of 8 on the b16 writes)
    #pragma unroll
    for (int c = 0; c < 4; ++c){
      const int kch = c*2 + (m16 >> 3);
      #pragma unroll
      for (int r = 0; r < 4; ++r){
        const int row = quad*4 + r;
        pw[(kch*16 + (row ^ kch))*8 + (m16 & 7)] = f2bf(sc[c][r]);
      }
    }
    asm volatile("s_waitcnt lgkmcnt(0)" ::: "memory");
    short8 pa0 = *(const short8*)prd0;
    short8 pa1 = *(const short8*)prd1;
    #pragma unroll
    for (int cn = 0; cn < 4; ++cn){
      Oa[cn] = mfma16(pa0, vf[2*cn], Oa[cn]);
      Oa[cn] = mfma16(pa1, vf[2*cn+1], Oa[cn]);
    }
  };

  LK(0, kA); LM(0, mA);
  for (int s0 = 0; s0 < 4096; s0 += 128){
    LK(s0+64, kB); LM(s0+64, mB);
    PROC(s0, kA, mA);
    if (s0 + 128 < 4096){ LK(s0+128, kA); LM(s0+128, mA); }
    PROC(s0+64, kB, mB);
  }

  const int b = bh >> 4, h = bh & 15;
  unsigned short* op = ctx + (((size_t)b*1024 + t0 + quad*4) << 10) + h*64 + m16;
  #pragma unroll
  for (int r = 0; r < 4; ++r){
    float inv = 1.f / lrow[r];
    #pragma unroll
    for (int cn = 0; cn < 4; ++cn)
      op[((size_t)r << 10) + cn*16] = f2bf(Oa[cn][r]*inv);
  }
}

extern "C" void kernel_launch(void* const* d_in, const int* in_sizes, int n_in,
                              void* d_out, int out_size, void* d_ws, size_t ws_size,
                              hipStream_t stream)
{
  (void)in_sizes; (void)n_in; (void)out_size; (void)ws_size;
  const float* hs    = (const float*)d_in[0];
  const float* mask  = (const float*)d_in[1];
  const float* pos   = (const float*)d_in[2];
  const float* kv    = (const float*)d_in[3];
  const float* kvpos = (const float*)d_in[4];
  const float* Wq = (const float*)d_in[5];  const float* biq = (const float*)d_in[6];
  const float* Wk = (const float*)d_in[7];  const float* bik = (const float*)d_in[8];
  const float* Wv = (const float*)d_in[9];  const float* biv = (const float*)d_in[10];
  const float* Wo = (const float*)d_in[11]; const float* bio = (const float*)d_in[12];
  float* out = (float*)d_out;
  char* ws = (char*)d_ws;
  unsigned short* Aq  = (unsigned short*)(ws + ( 0ull << 20));  // 4 MB
  unsigned short* Ak  = (unsigned short*)(ws + ( 4ull << 20));  // 16 MB
  unsigned short* Av  = (unsigned short*)(ws + (20ull << 20));  // 16 MB
  unsigned short* Wqb = (unsigned short*)(ws + (36ull << 20));  // 2 MB
  unsigned short* Wkb = (unsigned short*)(ws + (38ull << 20));  // 2 MB
  unsigned short* Wvb = (unsigned short*)(ws + (40ull << 20));  // 2 MB
  unsigned short* Wob = (unsigned short*)(ws + (42ull << 20));  // 2 MB
  unsigned short* Qb  = (unsigned short*)(ws + (44ull << 20));  // 4 MB
  unsigned short* Kb  = (unsigned short*)(ws + (48ull << 20));  // 16 MB
  unsigned short* VTb = (unsigned short*)(ws + (64ull << 20));  // 16 MB (end 80 MB)
  unsigned short* ctx = (unsigned short*)(ws + (36ull << 20));  // overlay Wqb/Wkb (dead)

  k_prep_all<<<dim3(14336), dim3(256), 0, stream>>>(
      (const float4*)hs, (const float4*)pos, (const float4*)kv, (const float4*)kvpos,
      (const float4*)Wq, (const float4*)Wk, (const float4*)Wv, (const float4*)Wo,
      (u16x4*)Aq, (u16x4*)Ak, (u16x4*)Av,
      (u16x4*)Wqb, (u16x4*)Wkb, (u16x4*)Wvb, (u16x4*)Wob);

  k_gemm<0><<<dim3(16, 8), dim3(256), 0, stream>>>(Aq, Wqb, biq, Qb, 2048, 0.125f);
  k_gemm<0><<<dim3(64, 8), dim3(256), 0, stream>>>(Ak, Wkb, bik, Kb, 8192, 1.0f);
  k_gemm<2><<<dim3(64, 8), dim3(256), 0, stream>>>(Av, Wvb, biv, VTb, 8192, 1.0f);
  k_flash<<<dim3(512), dim3(256), 0, stream>>>(Qb, Kb, VTb, mask, ctx);
  k_gemm<1><<<dim3(16, 8), dim3(256), 0, stream>>>(ctx, Wob, bio, out, 2048, 1.0f);
}